// Round 3
// baseline (662.260 us; speedup 1.0000x reference)
//
#include <hip/hip_runtime.h>
#include <hip/hip_bf16.h>

#define N_S 1024
#define N_R 768
#define LN_EPS 1e-5f
#define MEAN_EPS 1e-10f
#define LARGE_F 1e9f
#define QSCALE 0.35355339059327373f  // 8^-0.5

typedef __attribute__((ext_vector_type(8))) __bf16 bf16x8;
typedef __attribute__((ext_vector_type(4))) float f32x4;

__device__ __forceinline__ float bflo(unsigned u){ union{unsigned v; float f;} x; x.v = u << 16; return x.f; }
__device__ __forceinline__ unsigned short f2b(float f){
  __hip_bfloat16 h = __float2bfloat16(f);
  return *reinterpret_cast<unsigned short*>(&h);
}
__device__ __forceinline__ unsigned pk2(float a, float b){
  return (unsigned)f2b(a) | ((unsigned)f2b(b) << 16);
}
__device__ __forceinline__ bf16x8 ld_frag(const void* p){
  uint4 u = *reinterpret_cast<const uint4*>(p);
  return __builtin_bit_cast(bf16x8, u);
}

// ---- weight fragment prep: bf16 hi/lo fragments for gw (A=gw^T) and ow (A=ow^T) ----
__device__ __forceinline__ void weight_prep(int wave, int lane,
    const float* __restrict__ gw, const float* __restrict__ ow, uint4* __restrict__ wsf)
{
  #pragma unroll 1
  for (int rep = 0; rep < 2; rep++) {
    int fi = wave + rep * 4;              // 0..7
    int mf = fi >> 1, ks = fi & 1;
    int g = lane >> 4, c15 = lane & 15;
    union { uint4 u; unsigned short h[8]; } ghi, glo, ohi, olo;
    #pragma unroll
    for (int t = 0; t < 8; t++) {
      int k = ks * 32 + g * 8 + t;        // contraction index
      float gv = gw[k * 64 + mf * 16 + c15];
      unsigned short gh = f2b(gv);
      ghi.h[t] = gh;
      glo.h[t] = f2b(gv - bflo(gh));
      float ov = ow[k * 64 + mf * 16 + c15];
      unsigned short oh = f2b(ov);
      ohi.h[t] = oh;
      olo.h[t] = f2b(ov - bflo(oh));
    }
    wsf[(0 * 8 + fi) * 64 + lane] = ghi.u;
    wsf[(1 * 8 + fi) * 64 + lane] = glo.u;
    wsf[(2 * 8 + fi) * 64 + lane] = ohi.u;
    wsf[(3 * 8 + fi) * 64 + lane] = olo.u;
  }
}

// ============ kernel 1a: LN + K/V proj + masked-q partials (2 threads/row, 6144 blocks) ============
// thread pair (2j, 2j+1) owns row s; h = tid&1 selects channel half [h*32, h*32+32)
__global__ __launch_bounds__(256, 2) void lnkv_kernel(
    const float* __restrict__ act, const float* __restrict__ mask,
    const float* __restrict__ lns, const float* __restrict__ lnb,
    const float* __restrict__ kw,  const float* __restrict__ vw,
    const float* __restrict__ gw,  const float* __restrict__ ow,
    _Float16* __restrict__ kvws,   float* __restrict__ qpart,
    float* __restrict__ mpart,     uint4* __restrict__ wsf)
{
  __shared__ float redA[4][64];
  __shared__ float redB[4];

  const int tid  = threadIdx.x;
  const int lane = tid & 63;
  const int wave = tid >> 6;
  const int b    = blockIdx.x;

  if (b >= 6144) { weight_prep(wave, lane, gw, ow, wsf); return; }

  const int r  = b >> 3;
  const int sc = b & 7;
  const int s  = sc * 128 + (tid >> 1);
  const int h  = tid & 1;

  // load my half-row (32 f32)
  float rw[32];
  {
    const float4* rp = reinterpret_cast<const float4*>(
        act + ((size_t)s * N_R + r) * 64 + h * 32);
    #pragma unroll
    for (int i = 0; i < 8; i++) reinterpret_cast<float4*>(rw)[i] = rp[i];
  }
  float m = mask[(size_t)s * N_R + r];

  // LN stats across the pair
  float sum = 0.f, ss = 0.f;
  #pragma unroll
  for (int i = 0; i < 32; i++) { sum += rw[i]; ss += rw[i] * rw[i]; }
  sum += __shfl_xor(sum, 1);
  ss  += __shfl_xor(ss, 1);
  float mu  = sum * (1.f / 64.f);
  float rsd = rsqrtf(ss * (1.f / 64.f) - mu * mu + LN_EPS);

  // normalize + K/V partials over my 32 channels; rw becomes m*xn for the q-butterfly
  float kacc[8], vacc[8];
  #pragma unroll
  for (int d = 0; d < 8; d++) { kacc[d] = 0.f; vacc[d] = 0.f; }
  #pragma unroll
  for (int i = 0; i < 32; i++) {
    int c = h * 32 + i;
    float xn = fmaf((rw[i] - mu) * rsd, lns[c], lnb[c]);
    rw[i] = m * xn;
    #pragma unroll
    for (int d = 0; d < 8; d++) {
      kacc[d] = fmaf(xn, kw[c * 8 + d], kacc[d]);
      vacc[d] = fmaf(xn, vw[c * 8 + d], vacc[d]);
    }
  }
  // combine halves; even lane stores k, odd stores v (32B/row, fully coalesced)
  #pragma unroll
  for (int d = 0; d < 8; d++) {
    kacc[d] += __shfl_xor(kacc[d], 1);
    vacc[d] += __shfl_xor(vacc[d], 1);
  }
  {
    union { uint4 u; _Float16 hh[8]; } pk;
    #pragma unroll
    for (int d = 0; d < 8; d++) pk.hh[d] = (_Float16)(h ? vacc[d] : kacc[d]);
    *reinterpret_cast<uint4*>(kvws + ((size_t)r * N_S + s) * 16 + h * 8) = pk.u;
  }

  // in-place butterfly over 32 channel-partials; same-parity lanes share a channel half
  #pragma unroll
  for (int half = 16; half >= 1; half >>= 1) {
    const int stride = 32 / half;
    const bool hi = (lane & stride) != 0;
    #pragma unroll
    for (int i = 0; i < half; i++) {
      float gave = hi ? rw[i] : rw[i + half];
      float keep = hi ? rw[i + half] : rw[i];
      rw[i] = keep + __shfl_xor(gave, stride);
    }
  }
  // lane -> channel mapping of the surviving value
  {
    int local = (((lane >> 1) & 1) << 4) | (((lane >> 2) & 1) << 3) |
                (((lane >> 3) & 1) << 2) | (((lane >> 4) & 1) << 1) |
                ((lane >> 5) & 1);
    redA[wave][h * 32 + local] = rw[0];
  }
  float ms = h ? 0.f : m;
  #pragma unroll
  for (int o = 32; o > 0; o >>= 1) ms += __shfl_xor(ms, o);
  if (lane == 0) redB[wave] = ms;
  __syncthreads();
  if (tid < 64)
    qpart[((size_t)sc * N_R + r) * 64 + tid] =
        redA[0][tid] + redA[1][tid] + redA[2][tid] + redA[3][tid];
  if (tid == 64)
    mpart[sc * N_R + r] = redB[0] + redB[1] + redB[2] + redB[3];
}

// ============ kernel 1b: q formation + softmax + weighted_avg from K/V cache ============
__global__ __launch_bounds__(256, 2) void softmax_kernel(
    const float* __restrict__ mask, const float* __restrict__ qpart,
    const float* __restrict__ mpart, const float* __restrict__ qw,
    const _Float16* __restrict__ kvws, float* __restrict__ wavg_out)
{
  __shared__ float redA[4][64];
  __shared__ float redB[4][8];
  __shared__ float q_lds[64];
  __shared__ float qf_lds[64];

  const int tid  = threadIdx.x;
  const int lane = tid & 63;
  const int wave = tid >> 6;
  const int r    = blockIdx.x;

  if (tid < 64) {
    float qs = 0.f;
    #pragma unroll
    for (int p = 0; p < 8; p++) qs += qpart[((size_t)p * N_R + r) * 64 + tid];
    float mt = 0.f;
    #pragma unroll
    for (int p = 0; p < 8; p++) mt += mpart[p * N_R + r];
    q_lds[tid] = qs / (mt + MEAN_EPS);
  }
  __syncthreads();
  if (tid < 64) {
    float acc = 0.f;
    for (int c = 0; c < 64; c++) acc = fmaf(q_lds[c], qw[c * 64 + tid], acc);
    qf_lds[tid] = acc * QSCALE;
  }
  __syncthreads();

  float qreg[64];
  #pragma unroll
  for (int j = 0; j < 64; j++) qreg[j] = qf_lds[j];

  float ev[4][8];
  float hm[8];
  #pragma unroll
  for (int h = 0; h < 8; h++) hm[h] = -1e30f;

  #pragma unroll
  for (int it = 0; it < 4; it++) {
    int s = tid + it * 256;
    union { uint4 u; _Float16 h[8]; } kb;
    kb.u = *reinterpret_cast<const uint4*>(kvws + ((size_t)r * N_S + s) * 16);
    float kk[8];
    #pragma unroll
    for (int d = 0; d < 8; d++) kk[d] = (float)kb.h[d];
    float m = mask[(size_t)s * N_R + r];
    float bias = LARGE_F * (m - 1.f);
    #pragma unroll
    for (int h = 0; h < 8; h++) {
      float l = bias;
      #pragma unroll
      for (int d = 0; d < 8; d++) l = fmaf(qreg[h * 8 + d], kk[d], l);
      ev[it][h] = l;
      hm[h] = fmaxf(hm[h], l);
    }
  }
  #pragma unroll
  for (int h = 0; h < 8; h++) {
    #pragma unroll
    for (int o = 32; o > 0; o >>= 1) hm[h] = fmaxf(hm[h], __shfl_xor(hm[h], o));
  }
  if (lane == 0) {
    #pragma unroll
    for (int h = 0; h < 8; h++) redB[wave][h] = hm[h];
  }
  __syncthreads();
  #pragma unroll
  for (int h = 0; h < 8; h++)
    hm[h] = fmaxf(fmaxf(redB[0][h], redB[1][h]), fmaxf(redB[2][h], redB[3][h]));
  __syncthreads();  // redB reused for sums

  float hs[8];
  #pragma unroll
  for (int h = 0; h < 8; h++) hs[h] = 0.f;
  #pragma unroll
  for (int it = 0; it < 4; it++) {
    #pragma unroll
    for (int h = 0; h < 8; h++) {
      float e = __expf(ev[it][h] - hm[h]);
      ev[it][h] = e;
      hs[h] += e;
    }
  }
  #pragma unroll
  for (int h = 0; h < 8; h++) {
    #pragma unroll
    for (int o = 32; o > 0; o >>= 1) hs[h] += __shfl_xor(hs[h], o);
  }
  if (lane == 0) {
    #pragma unroll
    for (int h = 0; h < 8; h++) redB[wave][h] = hs[h];
  }
  __syncthreads();

  float wacc[64];
  #pragma unroll
  for (int j = 0; j < 64; j++) wacc[j] = 0.f;
  #pragma unroll
  for (int it = 0; it < 4; it++) {
    int s = tid + it * 256;
    union { uint4 u; _Float16 h[8]; } vb;
    vb.u = *reinterpret_cast<const uint4*>(kvws + ((size_t)r * N_S + s) * 16 + 8);
    float vv[8];
    #pragma unroll
    for (int d = 0; d < 8; d++) vv[d] = (float)vb.h[d];
    #pragma unroll
    for (int h = 0; h < 8; h++) {
      float w = ev[it][h];
      #pragma unroll
      for (int d = 0; d < 8; d++) wacc[h * 8 + d] = fmaf(w, vv[d], wacc[h * 8 + d]);
    }
  }
  #pragma unroll
  for (int j = 0; j < 64; j++) {
    #pragma unroll
    for (int o = 32; o > 0; o >>= 1) wacc[j] += __shfl_xor(wacc[j], o);
  }
  if (lane == 0) {
    #pragma unroll
    for (int j = 0; j < 64; j++) redA[wave][j] = wacc[j];
  }
  __syncthreads();
  if (tid < 64) {
    int h = tid >> 3;
    float hsv = redB[0][h] + redB[1][h] + redB[2][h] + redB[3][h];
    wavg_out[r * 64 + tid] =
        (redA[0][tid] + redA[1][tid] + redA[2][tid] + redA[3][tid]) / hsv;
  }
}

// ============ fallback stats kernel (R1 version) when workspace is small ============
struct SharedS { _Float16 kv[N_S][16]; };

__global__ __launch_bounds__(256, 2) void stats_kernel(
    const float* __restrict__ act, const float* __restrict__ mask,
    const float* __restrict__ lns, const float* __restrict__ lnb,
    const float* __restrict__ qw,  const float* __restrict__ kw,
    const float* __restrict__ vw,  const float* __restrict__ gw,
    const float* __restrict__ ow,  float* __restrict__ wavg_out,
    uint4* __restrict__ wsf)
{
  __shared__ SharedS sh;
  __shared__ float redA[4][64];
  __shared__ float redB[4][8];
  __shared__ float q_lds[64];
  __shared__ float qf_lds[64];

  const int tid  = threadIdx.x;
  const int lane = tid & 63;
  const int wave = tid >> 6;
  const int r    = blockIdx.x;

  if (r >= N_R) { weight_prep(wave, lane, gw, ow, wsf); return; }

  float qacc[64];
  #pragma unroll
  for (int c = 0; c < 64; c++) qacc[c] = 0.f;
  float msum = 0.f;

  #pragma unroll 1
  for (int it = 0; it < 4; it++) {
    int s = tid + it * 256;
    size_t base = ((size_t)s * N_R + r) * 64;
    float rw[64];
    const float4* rp = reinterpret_cast<const float4*>(act + base);
    #pragma unroll
    for (int i = 0; i < 16; i++) reinterpret_cast<float4*>(rw)[i] = rp[i];
    float m = mask[(size_t)s * N_R + r];
    float sum = 0.f, ss = 0.f;
    #pragma unroll
    for (int c = 0; c < 64; c++) { sum += rw[c]; ss += rw[c] * rw[c]; }
    float mu  = sum * (1.f / 64.f);
    float rsd = rsqrtf(ss * (1.f / 64.f) - mu * mu + LN_EPS);
    float kacc[8], vacc[8];
    #pragma unroll
    for (int d = 0; d < 8; d++) { kacc[d] = 0.f; vacc[d] = 0.f; }
    #pragma unroll
    for (int c = 0; c < 64; c++) {
      float xn = fmaf((rw[c] - mu) * rsd, lns[c], lnb[c]);
      qacc[c] = fmaf(m, xn, qacc[c]);
      #pragma unroll
      for (int d = 0; d < 8; d++) {
        kacc[d] = fmaf(xn, kw[c * 8 + d], kacc[d]);
        vacc[d] = fmaf(xn, vw[c * 8 + d], vacc[d]);
      }
    }
    union { uint4 u; _Float16 h[8]; } kb, vb;
    #pragma unroll
    for (int d = 0; d < 8; d++) { kb.h[d] = (_Float16)kacc[d]; vb.h[d] = (_Float16)vacc[d]; }
    *reinterpret_cast<uint4*>(&sh.kv[s][0]) = kb.u;
    *reinterpret_cast<uint4*>(&sh.kv[s][8]) = vb.u;
    msum += m;
  }

  #pragma unroll
  for (int c = 0; c < 64; c++) {
    #pragma unroll
    for (int o = 32; o > 0; o >>= 1) qacc[c] += __shfl_xor(qacc[c], o);
  }
  #pragma unroll
  for (int o = 32; o > 0; o >>= 1) msum += __shfl_xor(msum, o);
  if (lane == 0) {
    redB[wave][0] = msum;
    #pragma unroll
    for (int c = 0; c < 64; c++) redA[wave][c] = qacc[c];
  }
  __syncthreads();
  if (tid < 64) {
    float qs = redA[0][tid] + redA[1][tid] + redA[2][tid] + redA[3][tid];
    float mt = redB[0][0] + redB[1][0] + redB[2][0] + redB[3][0];
    q_lds[tid] = qs / (mt + MEAN_EPS);
  }
  __syncthreads();
  if (tid < 64) {
    float acc = 0.f;
    for (int c = 0; c < 64; c++) acc = fmaf(q_lds[c], qw[c * 64 + tid], acc);
    qf_lds[tid] = acc * QSCALE;
  }
  __syncthreads();

  float qreg[64];
  #pragma unroll
  for (int j = 0; j < 64; j++) qreg[j] = qf_lds[j];
  float ev[4][8];
  float hm[8];
  #pragma unroll
  for (int h = 0; h < 8; h++) hm[h] = -1e30f;
  #pragma unroll
  for (int it = 0; it < 4; it++) {
    int s = tid + it * 256;
    union { uint4 u; _Float16 h[8]; } kb;
    kb.u = *reinterpret_cast<uint4*>(&sh.kv[s][0]);
    float kk[8];
    #pragma unroll
    for (int d = 0; d < 8; d++) kk[d] = (float)kb.h[d];
    float m = mask[(size_t)s * N_R + r];
    float bias = LARGE_F * (m - 1.f);
    #pragma unroll
    for (int h = 0; h < 8; h++) {
      float l = bias;
      #pragma unroll
      for (int d = 0; d < 8; d++) l = fmaf(qreg[h * 8 + d], kk[d], l);
      ev[it][h] = l;
      hm[h] = fmaxf(hm[h], l);
    }
  }
  #pragma unroll
  for (int h = 0; h < 8; h++) {
    #pragma unroll
    for (int o = 32; o > 0; o >>= 1) hm[h] = fmaxf(hm[h], __shfl_xor(hm[h], o));
  }
  if (lane == 0) {
    #pragma unroll
    for (int h = 0; h < 8; h++) redB[wave][h] = hm[h];
  }
  __syncthreads();
  #pragma unroll
  for (int h = 0; h < 8; h++)
    hm[h] = fmaxf(fmaxf(redB[0][h], redB[1][h]), fmaxf(redB[2][h], redB[3][h]));
  __syncthreads();

  float hs[8];
  #pragma unroll
  for (int h = 0; h < 8; h++) hs[h] = 0.f;
  #pragma unroll
  for (int it = 0; it < 4; it++) {
    #pragma unroll
    for (int h = 0; h < 8; h++) {
      float e = __expf(ev[it][h] - hm[h]);
      ev[it][h] = e;
      hs[h] += e;
    }
  }
  #pragma unroll
  for (int h = 0; h < 8; h++) {
    #pragma unroll
    for (int o = 32; o > 0; o >>= 1) hs[h] += __shfl_xor(hs[h], o);
  }
  if (lane == 0) {
    #pragma unroll
    for (int h = 0; h < 8; h++) redB[wave][h] = hs[h];
  }
  __syncthreads();

  float wacc[64];
  #pragma unroll
  for (int j = 0; j < 64; j++) wacc[j] = 0.f;
  #pragma unroll
  for (int it = 0; it < 4; it++) {
    int s = tid + it * 256;
    union { uint4 u; _Float16 h[8]; } vb;
    vb.u = *reinterpret_cast<uint4*>(&sh.kv[s][8]);
    float vv[8];
    #pragma unroll
    for (int d = 0; d < 8; d++) vv[d] = (float)vb.h[d];
    #pragma unroll
    for (int h = 0; h < 8; h++) {
      float w = ev[it][h];
      #pragma unroll
      for (int d = 0; d < 8; d++) wacc[h * 8 + d] = fmaf(w, vv[d], wacc[h * 8 + d]);
    }
  }
  #pragma unroll
  for (int j = 0; j < 64; j++) {
    #pragma unroll
    for (int o = 32; o > 0; o >>= 1) wacc[j] += __shfl_xor(wacc[j], o);
  }
  if (lane == 0) {
    #pragma unroll
    for (int j = 0; j < 64; j++) redA[wave][j] = wacc[j];
  }
  __syncthreads();
  if (tid < 64) {
    int h = tid >> 3;
    float hsv = redB[0][h] + redB[1][h] + redB[2][h] + redB[3][h];
    wavg_out[r * 64 + tid] =
        (redA[0][tid] + redA[1][tid] + redA[2][tid] + redA[3][tid]) / hsv;
  }
}

// ============ kernel 2: persistent LN + gate GEMM + sigmoid*wavg + output GEMM (MFMA) ============
__device__ __forceinline__ void proj_tile(
    const float4 (&rv)[4], int t, int wv, int lane, int qr, int qc, int g, int c15,
    const float* __restrict__ lns, const float* __restrict__ lnb,
    const float* __restrict__ gb, const float* __restrict__ ob,
    const float* __restrict__ wavg, const uint4 (*wfrag)[64],
    char* my, float* __restrict__ out)
{
  const int r  = t >> 4;
  const int s0 = ((t & 15) << 6) + wv * 16;

  float sum = 0.f, ssq = 0.f;
  #pragma unroll
  for (int i = 0; i < 4; i++) {
    sum += rv[i].x + rv[i].y + rv[i].z + rv[i].w;
    ssq += rv[i].x * rv[i].x + rv[i].y * rv[i].y + rv[i].z * rv[i].z + rv[i].w * rv[i].w;
  }
  sum += __shfl_xor(sum, 1); ssq += __shfl_xor(ssq, 1);
  sum += __shfl_xor(sum, 2); ssq += __shfl_xor(ssq, 2);
  float mu  = sum * (1.f / 64.f);
  float rsd = rsqrtf(ssq * (1.f / 64.f) - mu * mu + LN_EPS);

  #pragma unroll
  for (int i = 0; i < 4; i++) {
    int c0 = 16 * i + 4 * qc;
    float4 s4 = *reinterpret_cast<const float4*>(lns + c0);
    float4 b4 = *reinterpret_cast<const float4*>(lnb + c0);
    float x0 = fmaf((rv[i].x - mu) * rsd, s4.x, b4.x);
    float x1 = fmaf((rv[i].y - mu) * rsd, s4.y, b4.y);
    float x2 = fmaf((rv[i].z - mu) * rsd, s4.z, b4.z);
    float x3 = fmaf((rv[i].w - mu) * rsd, s4.w, b4.w);
    uint2 p; p.x = pk2(x0, x1); p.y = pk2(x2, x3);
    int byt = ((2 * i + (qc >> 1)) << 8) + (qr << 4) + ((qc & 1) << 3);
    *reinterpret_cast<uint2*>(my + byt) = p;
  }
  asm volatile("" ::: "memory");
  bf16x8 xb0 = ld_frag(my + lane * 16);
  bf16x8 xb1 = ld_frag(my + 1024 + lane * 16);

  const f32x4 zero = {0.f, 0.f, 0.f, 0.f};
  f32x4 acc[4] = {zero, zero, zero, zero};
  #pragma unroll
  for (int mf = 0; mf < 4; mf++) {
    acc[mf] = __builtin_amdgcn_mfma_f32_16x16x32_bf16(ld_frag(&wfrag[     mf*2    ][lane]), xb0, acc[mf], 0, 0, 0);
    acc[mf] = __builtin_amdgcn_mfma_f32_16x16x32_bf16(ld_frag(&wfrag[ 8 + mf*2    ][lane]), xb0, acc[mf], 0, 0, 0);
    acc[mf] = __builtin_amdgcn_mfma_f32_16x16x32_bf16(ld_frag(&wfrag[     mf*2 + 1][lane]), xb1, acc[mf], 0, 0, 0);
    acc[mf] = __builtin_amdgcn_mfma_f32_16x16x32_bf16(ld_frag(&wfrag[ 8 + mf*2 + 1][lane]), xb1, acc[mf], 0, 0, 0);
  }

  // coef = wavg[j] * sigmoid(G + gb[j]); reuses the x staging bytes (x frags already consumed)
  asm volatile("" ::: "memory");
  #pragma unroll
  for (int mf = 0; mf < 4; mf++) {
    int jb = mf * 16 + 4 * g;
    float4 wv4 = *reinterpret_cast<const float4*>(wavg + r * 64 + jb);
    float4 gb4 = *reinterpret_cast<const float4*>(gb + jb);
    float c0 = wv4.x / (1.f + __expf(-(acc[mf][0] + gb4.x)));
    float c1 = wv4.y / (1.f + __expf(-(acc[mf][1] + gb4.y)));
    float c2 = wv4.z / (1.f + __expf(-(acc[mf][2] + gb4.z)));
    float c3 = wv4.w / (1.f + __expf(-(acc[mf][3] + gb4.w)));
    uint2 p; p.x = pk2(c0, c1); p.y = pk2(c2, c3);
    int byt = ((2 * mf + (g >> 1)) << 8) + (c15 << 4) + ((g & 1) << 3);
    *reinterpret_cast<uint2*>(my + byt) = p;
  }
  asm volatile("" ::: "memory");
  bf16x8 cb0 = ld_frag(my + lane * 16);
  bf16x8 cb1 = ld_frag(my + 1024 + lane * 16);

  f32x4 acc2[4] = {zero, zero, zero, zero};
  #pragma unroll
  for (int mf = 0; mf < 4; mf++) {
    acc2[mf] = __builtin_amdgcn_mfma_f32_16x16x32_bf16(ld_frag(&wfrag[16 + mf*2    ][lane]), cb0, acc2[mf], 0, 0, 0);
    acc2[mf] = __builtin_amdgcn_mfma_f32_16x16x32_bf16(ld_frag(&wfrag[24 + mf*2    ][lane]), cb0, acc2[mf], 0, 0, 0);
    acc2[mf] = __builtin_amdgcn_mfma_f32_16x16x32_bf16(ld_frag(&wfrag[16 + mf*2 + 1][lane]), cb1, acc2[mf], 0, 0, 0);
    acc2[mf] = __builtin_amdgcn_mfma_f32_16x16x32_bf16(ld_frag(&wfrag[24 + mf*2 + 1][lane]), cb1, acc2[mf], 0, 0, 0);
  }

  // direct store: lane holds out[s = s0+c15][o = mf*16+4g .. +3]
  size_t obase = ((size_t)(s0 + c15) * N_R + r) * 64;
  #pragma unroll
  for (int mf = 0; mf < 4; mf++) {
    int o0 = mf * 16 + 4 * g;
    float4 e = *reinterpret_cast<const float4*>(ob + o0);
    float4 o4;
    o4.x = acc2[mf][0] + e.x;
    o4.y = acc2[mf][1] + e.y;
    o4.z = acc2[mf][2] + e.z;
    o4.w = acc2[mf][3] + e.w;
    *reinterpret_cast<float4*>(out + obase + o0) = o4;
  }
}

__global__ __launch_bounds__(256, 4) void proj_kernel(
    const float* __restrict__ act, const float* __restrict__ lns,
    const float* __restrict__ lnb, const float* __restrict__ gb,
    const float* __restrict__ ob,  const float* __restrict__ wavg,
    const uint4* __restrict__ wsf, float* __restrict__ out)
{
  __shared__ uint4 wfrag[32][64];              // 32 KiB weight fragments
  __shared__ __align__(16) char wbuf[4][2048]; // 8 KiB per-wave x/coef staging

  const int tid  = threadIdx.x;
  const int lane = tid & 63;
  const int wv   = tid >> 6;
  const int b    = blockIdx.x;
  const int qr = lane >> 2, qc = lane & 3;
  const int g = lane >> 4, c15 = lane & 15;
  char* my = wbuf[wv];

  // tile 0 prefetch overlaps the wfrag staging
  float4 rvA[4], rvB[4];
  {
    int t = b;
    const float4* ap = reinterpret_cast<const float4*>(
        act + ((size_t)((((t & 15) << 6) + wv * 16) + qr) * N_R + (t >> 4)) * 64);
    rvA[0] = ap[qc]; rvA[1] = ap[qc + 4]; rvA[2] = ap[qc + 8]; rvA[3] = ap[qc + 12];
  }
  {
    uint4* dst = &wfrag[0][0];
    #pragma unroll
    for (int i = 0; i < 8; i++) dst[tid + i * 256] = wsf[tid + i * 256];
  }
  __syncthreads();

  #pragma unroll 1
  for (int i = 0; i < 12; i += 2) {
    {
      int t = (i + 1) * 1024 + b;
      const float4* ap = reinterpret_cast<const float4*>(
          act + ((size_t)((((t & 15) << 6) + wv * 16) + qr) * N_R + (t >> 4)) * 64);
      rvB[0] = ap[qc]; rvB[1] = ap[qc + 4]; rvB[2] = ap[qc + 8]; rvB[3] = ap[qc + 12];
    }
    proj_tile(rvA, i * 1024 + b, wv, lane, qr, qc, g, c15, lns, lnb, gb, ob, wavg, wfrag, my, out);
    if (i + 2 < 12) {
      int t = (i + 2) * 1024 + b;
      const float4* ap = reinterpret_cast<const float4*>(
          act + ((size_t)((((t & 15) << 6) + wv * 16) + qr) * N_R + (t >> 4)) * 64);
      rvA[0] = ap[qc]; rvA[1] = ap[qc + 4]; rvA[2] = ap[qc + 8]; rvA[3] = ap[qc + 12];
    }
    proj_tile(rvB, (i + 1) * 1024 + b, wv, lane, qr, qc, g, c15, lns, lnb, gb, ob, wavg, wfrag, my, out);
  }
}

extern "C" void kernel_launch(void* const* d_in, const int* in_sizes, int n_in,
                              void* d_out, int out_size, void* d_ws, size_t ws_size,
                              hipStream_t stream)
{
  const float* act  = (const float*)d_in[0];
  const float* mask = (const float*)d_in[1];
  const float* lns  = (const float*)d_in[2];
  const float* lnb  = (const float*)d_in[3];
  const float* qw   = (const float*)d_in[4];
  const float* kw   = (const float*)d_in[5];
  const float* vw   = (const float*)d_in[6];
  const float* gw   = (const float*)d_in[7];
  const float* gb   = (const float*)d_in[8];
  const float* ow   = (const float*)d_in[9];
  const float* ob   = (const float*)d_in[10];

  char* ws = (char*)d_ws;
  float* wavg_ws = (float*)ws;                       // 196608 B
  uint4* wsf     = (uint4*)(ws + 196608);            // 32768 B
  const size_t OFF_KV = 229376;                      // fp16 [768][1024][16] = 25165824 B
  const size_t OFF_QP = OFF_KV + 25165824;           // f32 [8][768][64] = 1572864 B
  const size_t OFF_MP = OFF_QP + 1572864;            // f32 [8][768] = 24576 B
  const size_t NEED   = OFF_MP + 24576;

  if (ws_size >= NEED) {
    _Float16* kvws = (_Float16*)(ws + OFF_KV);
    float* qpart   = (float*)(ws + OFF_QP);
    float* mpart   = (float*)(ws + OFF_MP);
    lnkv_kernel<<<6145, 256, 0, stream>>>(act, mask, lns, lnb, kw, vw, gw, ow,
                                          kvws, qpart, mpart, wsf);
    softmax_kernel<<<N_R, 256, 0, stream>>>(mask, qpart, mpart, qw, kvws, wavg_ws);
  } else {
    stats_kernel<<<N_R + 1, 256, 0, stream>>>(act, mask, lns, lnb, qw, kw, vw,
                                              gw, ow, wavg_ws, wsf);
  }
  proj_kernel<<<1024, 256, 0, stream>>>(act, lns, lnb, gb, ob,
                                        wavg_ws, (const uint4*)wsf, (float*)d_out);
}

// Round 4
// 574.587 us; speedup vs baseline: 1.1526x; 1.1526x over previous
//
#include <hip/hip_runtime.h>
#include <hip/hip_bf16.h>

#define N_S 1024
#define N_R 768
#define LN_EPS 1e-5f
#define MEAN_EPS 1e-10f
#define LARGE_F 1e9f
#define QSCALE 0.35355339059327373f  // 8^-0.5

typedef __attribute__((ext_vector_type(8))) __bf16 bf16x8;
typedef __attribute__((ext_vector_type(4))) float f32x4;

__device__ __forceinline__ float bflo(unsigned u){ union{unsigned v; float f;} x; x.v = u << 16; return x.f; }
__device__ __forceinline__ unsigned short f2b(float f){
  __hip_bfloat16 h = __float2bfloat16(f);
  return *reinterpret_cast<unsigned short*>(&h);
}
__device__ __forceinline__ unsigned pk2(float a, float b){
  return (unsigned)f2b(a) | ((unsigned)f2b(b) << 16);
}
__device__ __forceinline__ bf16x8 ld_frag(const void* p){
  uint4 u = *reinterpret_cast<const uint4*>(p);
  return __builtin_bit_cast(bf16x8, u);
}

// ---- weight fragment prep: bf16 hi/lo fragments for gw (A=gw^T) and ow (A=ow^T) ----
__device__ __forceinline__ void weight_prep(int wave, int lane,
    const float* __restrict__ gw, const float* __restrict__ ow, uint4* __restrict__ wsf)
{
  #pragma unroll 1
  for (int rep = 0; rep < 2; rep++) {
    int fi = wave + rep * 4;              // 0..7
    int mf = fi >> 1, ks = fi & 1;
    int g = lane >> 4, c15 = lane & 15;
    union { uint4 u; unsigned short h[8]; } ghi, glo, ohi, olo;
    #pragma unroll
    for (int t = 0; t < 8; t++) {
      int k = ks * 32 + g * 8 + t;        // contraction index
      float gv = gw[k * 64 + mf * 16 + c15];
      unsigned short gh = f2b(gv);
      ghi.h[t] = gh;
      glo.h[t] = f2b(gv - bflo(gh));
      float ov = ow[k * 64 + mf * 16 + c15];
      unsigned short oh = f2b(ov);
      ohi.h[t] = oh;
      olo.h[t] = f2b(ov - bflo(oh));
    }
    wsf[(0 * 8 + fi) * 64 + lane] = ghi.u;
    wsf[(1 * 8 + fi) * 64 + lane] = glo.u;
    wsf[(2 * 8 + fi) * 64 + lane] = ohi.u;
    wsf[(3 * 8 + fi) * 64 + lane] = olo.u;
  }
}

// ============ kernel A: LN + K/V proj + q partials (+ xnf fragment staging if BIG) ============
// grid 1536(+1): block b -> r-chunk rcb = b>>5 (16 r), s-chunk sc = b&31 (32 s).
// thread: rl = lane&15 -> r = rcb*16+rl; sl = tid>>4 -> rows s = sc*32 + sl*2 + {0,1}.
// Full 64-ch row per thread => kw/vw addresses wave-uniform => scalar loads.
template<bool BIG>
__global__ __launch_bounds__(256, 2) void lnkv2_kernel(
    const float* __restrict__ act, const float* __restrict__ mask,
    const float* __restrict__ lns, const float* __restrict__ lnb,
    const float* __restrict__ kw,  const float* __restrict__ vw,
    const float* __restrict__ gw,  const float* __restrict__ ow,
    _Float16* __restrict__ kvws,   float* __restrict__ qpart,
    uint4* __restrict__ xnf,       uint4* __restrict__ wsf)
{
  __shared__ float wsum[4][16][64];   // 16 KiB

  const int tid  = threadIdx.x;
  const int lane = tid & 63;
  const int wave = tid >> 6;
  const int b    = blockIdx.x;

  if (b >= 1536) { weight_prep(wave, lane, gw, ow, wsf); return; }

  const int rcb = b >> 5;
  const int sc  = b & 31;
  const int r0  = rcb * 16;
  const int rl  = lane & 15;
  const int sl  = tid >> 4;
  const int r   = r0 + rl;
  // butterfly channel base for this lane (bits 4,5 are the s-group)
  const int chA = (((lane >> 5) & 1) << 4) | (((lane >> 4) & 1) << 5);

  float qacc[16];
  #pragma unroll
  for (int i = 0; i < 16; i++) qacc[i] = 0.f;

  #pragma unroll 1
  for (int k = 0; k < 2; k++) {
    const int s = sc * 32 + sl * 2 + k;
    const size_t rowbase = ((size_t)s * N_R + r) * 64;

    float rw[64];
    {
      const float4* rp = reinterpret_cast<const float4*>(act + rowbase);
      #pragma unroll
      for (int i = 0; i < 16; i++) reinterpret_cast<float4*>(rw)[i] = rp[i];
    }
    float m = mask[(size_t)s * N_R + r];

    float sum = 0.f, ss = 0.f;
    #pragma unroll
    for (int c = 0; c < 64; c++) { sum += rw[c]; ss += rw[c] * rw[c]; }
    float mu  = sum * (1.f / 64.f);
    float rsd = rsqrtf(ss * (1.f / 64.f) - mu * mu + LN_EPS);

    float kacc[8], vacc[8];
    #pragma unroll
    for (int d = 0; d < 8; d++) { kacc[d] = 0.f; vacc[d] = 0.f; }
    #pragma unroll
    for (int c = 0; c < 64; c++) {
      float xn = fmaf((rw[c] - mu) * rsd, lns[c], lnb[c]);
      rw[c] = xn;
      #pragma unroll
      for (int d = 0; d < 8; d++) {
        kacc[d] = fmaf(xn, kw[c * 8 + d], kacc[d]);
        vacc[d] = fmaf(xn, vw[c * 8 + d], vacc[d]);
      }
    }
    {
      union { uint4 u; _Float16 hh[8]; } kb, vb;
      #pragma unroll
      for (int d = 0; d < 8; d++) { kb.hh[d] = (_Float16)kacc[d]; vb.hh[d] = (_Float16)vacc[d]; }
      _Float16* kvp = kvws + ((size_t)r * N_S + s) * 16;
      *reinterpret_cast<uint4*>(kvp)     = kb.u;
      *reinterpret_cast<uint4*>(kvp + 8) = vb.u;
    }

    if (BIG) {
      // stage xn bf16 in MFMA B-fragment order: tile t = rcb*1024 + s;
      // byte-in-tile = (oct>>2)*1024 + (oct&3)*256 + rl*16, oct = c>>3
      const size_t tb = ((size_t)rcb * 1024 + s) * 128;   // uint4 units
      #pragma unroll
      for (int oct = 0; oct < 8; oct++) {
        uint4 w;
        w.x = pk2(rw[oct * 8 + 0], rw[oct * 8 + 1]);
        w.y = pk2(rw[oct * 8 + 2], rw[oct * 8 + 3]);
        w.z = pk2(rw[oct * 8 + 4], rw[oct * 8 + 5]);
        w.w = pk2(rw[oct * 8 + 6], rw[oct * 8 + 7]);
        xnf[tb + (oct >> 2) * 64 + (oct & 3) * 16 + rl] = w;
      }
    }

    // masked q: scale then 2-step butterfly over lane bits 4,5 (sum over the 4-lane s-group)
    #pragma unroll
    for (int c = 0; c < 64; c++) rw[c] *= m;
    {
      const bool hi = (lane & 16) != 0;
      #pragma unroll
      for (int i = 0; i < 32; i++) {
        float gave = hi ? rw[i] : rw[i + 32];
        float keep = hi ? rw[i + 32] : rw[i];
        rw[i] = keep + __shfl_xor(gave, 16);
      }
    }
    {
      const bool hi = (lane & 32) != 0;
      #pragma unroll
      for (int i = 0; i < 16; i++) {
        float gave = hi ? rw[i] : rw[i + 16];
        float keep = hi ? rw[i + 16] : rw[i];
        rw[i] = keep + __shfl_xor(gave, 32);
      }
    }
    #pragma unroll
    for (int i = 0; i < 16; i++) qacc[i] += rw[i];
  }

  #pragma unroll
  for (int i = 0; i < 16; i++) wsum[wave][rl][i + chA] = qacc[i];
  __syncthreads();

  {
    const int rl2 = tid >> 4;
    const int c0  = (tid & 15) * 4;
    float4 a = *reinterpret_cast<const float4*>(&wsum[0][rl2][c0]);
    float4 b1 = *reinterpret_cast<const float4*>(&wsum[1][rl2][c0]);
    float4 c1 = *reinterpret_cast<const float4*>(&wsum[2][rl2][c0]);
    float4 d1 = *reinterpret_cast<const float4*>(&wsum[3][rl2][c0]);
    float4 o;
    o.x = a.x + b1.x + c1.x + d1.x;
    o.y = a.y + b1.y + c1.y + d1.y;
    o.z = a.z + b1.z + c1.z + d1.z;
    o.w = a.w + b1.w + c1.w + d1.w;
    *reinterpret_cast<float4*>(&qpart[((size_t)sc * N_R + r0 + rl2) * 64 + c0]) = o;
  }
}

// ============ kernel B: q formation + softmax + weighted_avg ============
__global__ __launch_bounds__(256, 2) void softmax2_kernel(
    const float* __restrict__ mask, const float* __restrict__ qpart,
    const float* __restrict__ qw,   const _Float16* __restrict__ kvws,
    float* __restrict__ wavg_out)
{
  __shared__ float redA[4][64];
  __shared__ float redB[4][8];
  __shared__ float redM[4];
  __shared__ float q_lds[64];
  __shared__ float qf_lds[64];

  const int tid  = threadIdx.x;
  const int lane = tid & 63;
  const int wave = tid >> 6;
  const int r    = blockIdx.x;

  // mask row + msum
  float mreg[4];
  #pragma unroll
  for (int it = 0; it < 4; it++) mreg[it] = mask[(size_t)(tid + it * 256) * N_R + r];
  {
    float ms = mreg[0] + mreg[1] + mreg[2] + mreg[3];
    #pragma unroll
    for (int o = 32; o > 0; o >>= 1) ms += __shfl_xor(ms, o);
    if (lane == 0) redM[wave] = ms;
  }
  __syncthreads();
  if (tid < 64) {
    float qs = 0.f;
    #pragma unroll 1
    for (int p = 0; p < 32; p++) qs += qpart[((size_t)p * N_R + r) * 64 + tid];
    float mt = redM[0] + redM[1] + redM[2] + redM[3];
    q_lds[tid] = qs / (mt + MEAN_EPS);
  }
  __syncthreads();
  if (tid < 64) {
    float acc = 0.f;
    for (int c = 0; c < 64; c++) acc = fmaf(q_lds[c], qw[c * 64 + tid], acc);
    qf_lds[tid] = acc * QSCALE;
  }
  __syncthreads();

  float qreg[64];
  #pragma unroll
  for (int j = 0; j < 64; j++) qreg[j] = qf_lds[j];

  float ev[4][8];
  float hm[8];
  #pragma unroll
  for (int h = 0; h < 8; h++) hm[h] = -1e30f;

  #pragma unroll
  for (int it = 0; it < 4; it++) {
    int s = tid + it * 256;
    union { uint4 u; _Float16 h[8]; } kb;
    kb.u = *reinterpret_cast<const uint4*>(kvws + ((size_t)r * N_S + s) * 16);
    float kk[8];
    #pragma unroll
    for (int d = 0; d < 8; d++) kk[d] = (float)kb.h[d];
    float bias = LARGE_F * (mreg[it] - 1.f);
    #pragma unroll
    for (int h = 0; h < 8; h++) {
      float l = bias;
      #pragma unroll
      for (int d = 0; d < 8; d++) l = fmaf(qreg[h * 8 + d], kk[d], l);
      ev[it][h] = l;
      hm[h] = fmaxf(hm[h], l);
    }
  }
  #pragma unroll
  for (int h = 0; h < 8; h++) {
    #pragma unroll
    for (int o = 32; o > 0; o >>= 1) hm[h] = fmaxf(hm[h], __shfl_xor(hm[h], o));
  }
  if (lane == 0) {
    #pragma unroll
    for (int h = 0; h < 8; h++) redB[wave][h] = hm[h];
  }
  __syncthreads();
  #pragma unroll
  for (int h = 0; h < 8; h++)
    hm[h] = fmaxf(fmaxf(redB[0][h], redB[1][h]), fmaxf(redB[2][h], redB[3][h]));
  __syncthreads();  // redB reused for sums

  float hs[8];
  #pragma unroll
  for (int h = 0; h < 8; h++) hs[h] = 0.f;
  #pragma unroll
  for (int it = 0; it < 4; it++) {
    #pragma unroll
    for (int h = 0; h < 8; h++) {
      float e = __expf(ev[it][h] - hm[h]);
      ev[it][h] = e;
      hs[h] += e;
    }
  }
  #pragma unroll
  for (int h = 0; h < 8; h++) {
    #pragma unroll
    for (int o = 32; o > 0; o >>= 1) hs[h] += __shfl_xor(hs[h], o);
  }
  if (lane == 0) {
    #pragma unroll
    for (int h = 0; h < 8; h++) redB[wave][h] = hs[h];
  }
  __syncthreads();

  float wacc[64];
  #pragma unroll
  for (int j = 0; j < 64; j++) wacc[j] = 0.f;
  #pragma unroll
  for (int it = 0; it < 4; it++) {
    int s = tid + it * 256;
    union { uint4 u; _Float16 h[8]; } vb;
    vb.u = *reinterpret_cast<const uint4*>(kvws + ((size_t)r * N_S + s) * 16 + 8);
    float vv[8];
    #pragma unroll
    for (int d = 0; d < 8; d++) vv[d] = (float)vb.h[d];
    #pragma unroll
    for (int h = 0; h < 8; h++) {
      float w = ev[it][h];
      #pragma unroll
      for (int d = 0; d < 8; d++) wacc[h * 8 + d] = fmaf(w, vv[d], wacc[h * 8 + d]);
    }
  }
  #pragma unroll
  for (int j = 0; j < 64; j++) {
    #pragma unroll
    for (int o = 32; o > 0; o >>= 1) wacc[j] += __shfl_xor(wacc[j], o);
  }
  if (lane == 0) {
    #pragma unroll
    for (int j = 0; j < 64; j++) redA[wave][j] = wacc[j];
  }
  __syncthreads();
  if (tid < 64) {
    int h = tid >> 3;
    float hsv = redB[0][h] + redB[1][h] + redB[2][h] + redB[3][h];
    wavg_out[r * 64 + tid] =
        (redA[0][tid] + redA[1][tid] + redA[2][tid] + redA[3][tid]) / hsv;
  }
}

// ============ kernel C (BIG): gate GEMM + sigmoid*wavg + output GEMM from xnf fragments ============
// tiles t = rc*1024 + s: 16 rows (s, rc*16..rc*16+15). grid 1024 x 4 waves x 12 iters.
__global__ __launch_bounds__(256, 4) void proj2_kernel(
    const uint4* __restrict__ xnf, const float* __restrict__ gb,
    const float* __restrict__ ob,  const float* __restrict__ wavg,
    const uint4* __restrict__ wsf, float* __restrict__ out)
{
  __shared__ uint4 wfrag[32][64];              // 32 KiB weight fragments
  __shared__ __align__(16) char wbuf[4][2048]; // per-wave coef staging

  const int tid  = threadIdx.x;
  const int lane = tid & 63;
  const int wv   = tid >> 6;
  const int b    = blockIdx.x;
  const int g = lane >> 4, c15 = lane & 15;
  char* my = wbuf[wv];

  {
    uint4* dst = &wfrag[0][0];
    #pragma unroll
    for (int i = 0; i < 8; i++) dst[tid + i * 256] = wsf[tid + i * 256];
  }
  __syncthreads();

  const f32x4 zero = {0.f, 0.f, 0.f, 0.f};

  #pragma unroll 1
  for (int i = 0; i < 12; i++) {
    const int t  = i * 4096 + b * 4 + wv;
    const int rc = t >> 10, s = t & 1023;
    const int r0 = rc << 4;
    const uint4* tb = xnf + (size_t)t * 128;

    bf16x8 xb0 = ld_frag(tb + lane);
    bf16x8 xb1 = ld_frag(tb + 64 + lane);

    f32x4 acc[4] = {zero, zero, zero, zero};
    #pragma unroll
    for (int mf = 0; mf < 4; mf++) {
      acc[mf] = __builtin_amdgcn_mfma_f32_16x16x32_bf16(ld_frag(&wfrag[     mf*2    ][lane]), xb0, acc[mf], 0, 0, 0);
      acc[mf] = __builtin_amdgcn_mfma_f32_16x16x32_bf16(ld_frag(&wfrag[ 8 + mf*2    ][lane]), xb0, acc[mf], 0, 0, 0);
      acc[mf] = __builtin_amdgcn_mfma_f32_16x16x32_bf16(ld_frag(&wfrag[     mf*2 + 1][lane]), xb1, acc[mf], 0, 0, 0);
      acc[mf] = __builtin_amdgcn_mfma_f32_16x16x32_bf16(ld_frag(&wfrag[ 8 + mf*2 + 1][lane]), xb1, acc[mf], 0, 0, 0);
    }

    // coef = wavg[r0+c15][j] * sigmoid(G + gb[j]) -> bf16 -> B-frag staging
    asm volatile("" ::: "memory");
    #pragma unroll
    for (int mf = 0; mf < 4; mf++) {
      int jb = mf * 16 + 4 * g;
      float4 wv4 = *reinterpret_cast<const float4*>(wavg + (r0 + c15) * 64 + jb);
      float4 gb4 = *reinterpret_cast<const float4*>(gb + jb);
      float c0 = wv4.x / (1.f + __expf(-(acc[mf][0] + gb4.x)));
      float c1 = wv4.y / (1.f + __expf(-(acc[mf][1] + gb4.y)));
      float c2 = wv4.z / (1.f + __expf(-(acc[mf][2] + gb4.z)));
      float c3 = wv4.w / (1.f + __expf(-(acc[mf][3] + gb4.w)));
      uint2 p; p.x = pk2(c0, c1); p.y = pk2(c2, c3);
      int byt = ((2 * mf + (g >> 1)) << 8) + (c15 << 4) + ((g & 1) << 3);
      *reinterpret_cast<uint2*>(my + byt) = p;
    }
    asm volatile("" ::: "memory");
    bf16x8 cb0 = ld_frag(my + lane * 16);
    bf16x8 cb1 = ld_frag(my + 1024 + lane * 16);

    f32x4 acc2[4] = {zero, zero, zero, zero};
    #pragma unroll
    for (int mf = 0; mf < 4; mf++) {
      acc2[mf] = __builtin_amdgcn_mfma_f32_16x16x32_bf16(ld_frag(&wfrag[16 + mf*2    ][lane]), cb0, acc2[mf], 0, 0, 0);
      acc2[mf] = __builtin_amdgcn_mfma_f32_16x16x32_bf16(ld_frag(&wfrag[24 + mf*2    ][lane]), cb0, acc2[mf], 0, 0, 0);
      acc2[mf] = __builtin_amdgcn_mfma_f32_16x16x32_bf16(ld_frag(&wfrag[16 + mf*2 + 1][lane]), cb1, acc2[mf], 0, 0, 0);
      acc2[mf] = __builtin_amdgcn_mfma_f32_16x16x32_bf16(ld_frag(&wfrag[24 + mf*2 + 1][lane]), cb1, acc2[mf], 0, 0, 0);
    }

    asm volatile("" ::: "memory");
    // store: lane holds out[s][r0+c15][o0..o0+3]
    const size_t obase = ((size_t)s * N_R + r0 + c15) * 64;
    #pragma unroll
    for (int mf = 0; mf < 4; mf++) {
      int o0 = mf * 16 + 4 * g;
      float4 e = *reinterpret_cast<const float4*>(ob + o0);
      float4 o4;
      o4.x = acc2[mf][0] + e.x;
      o4.y = acc2[mf][1] + e.y;
      o4.z = acc2[mf][2] + e.z;
      o4.w = acc2[mf][3] + e.w;
      *reinterpret_cast<float4*>(out + obase + o0) = o4;
    }
  }
}

// ============ fallback stats kernel (R1 version) ============
struct SharedS { _Float16 kv[N_S][16]; };

__global__ __launch_bounds__(256, 2) void stats_kernel(
    const float* __restrict__ act, const float* __restrict__ mask,
    const float* __restrict__ lns, const float* __restrict__ lnb,
    const float* __restrict__ qw,  const float* __restrict__ kw,
    const float* __restrict__ vw,  const float* __restrict__ gw,
    const float* __restrict__ ow,  float* __restrict__ wavg_out,
    uint4* __restrict__ wsf)
{
  __shared__ SharedS sh;
  __shared__ float redA[4][64];
  __shared__ float redB[4][8];
  __shared__ float q_lds[64];
  __shared__ float qf_lds[64];

  const int tid  = threadIdx.x;
  const int lane = tid & 63;
  const int wave = tid >> 6;
  const int r    = blockIdx.x;

  if (r >= N_R) { weight_prep(wave, lane, gw, ow, wsf); return; }

  float qacc[64];
  #pragma unroll
  for (int c = 0; c < 64; c++) qacc[c] = 0.f;
  float msum = 0.f;

  #pragma unroll 1
  for (int it = 0; it < 4; it++) {
    int s = tid + it * 256;
    size_t base = ((size_t)s * N_R + r) * 64;
    float rw[64];
    const float4* rp = reinterpret_cast<const float4*>(act + base);
    #pragma unroll
    for (int i = 0; i < 16; i++) reinterpret_cast<float4*>(rw)[i] = rp[i];
    float m = mask[(size_t)s * N_R + r];
    float sum = 0.f, ss = 0.f;
    #pragma unroll
    for (int c = 0; c < 64; c++) { sum += rw[c]; ss += rw[c] * rw[c]; }
    float mu  = sum * (1.f / 64.f);
    float rsd = rsqrtf(ss * (1.f / 64.f) - mu * mu + LN_EPS);
    float kacc[8], vacc[8];
    #pragma unroll
    for (int d = 0; d < 8; d++) { kacc[d] = 0.f; vacc[d] = 0.f; }
    #pragma unroll
    for (int c = 0; c < 64; c++) {
      float xn = fmaf((rw[c] - mu) * rsd, lns[c], lnb[c]);
      qacc[c] = fmaf(m, xn, qacc[c]);
      #pragma unroll
      for (int d = 0; d < 8; d++) {
        kacc[d] = fmaf(xn, kw[c * 8 + d], kacc[d]);
        vacc[d] = fmaf(xn, vw[c * 8 + d], vacc[d]);
      }
    }
    union { uint4 u; _Float16 h[8]; } kb, vb;
    #pragma unroll
    for (int d = 0; d < 8; d++) { kb.h[d] = (_Float16)kacc[d]; vb.h[d] = (_Float16)vacc[d]; }
    *reinterpret_cast<uint4*>(&sh.kv[s][0]) = kb.u;
    *reinterpret_cast<uint4*>(&sh.kv[s][8]) = vb.u;
    msum += m;
  }

  #pragma unroll
  for (int c = 0; c < 64; c++) {
    #pragma unroll
    for (int o = 32; o > 0; o >>= 1) qacc[c] += __shfl_xor(qacc[c], o);
  }
  #pragma unroll
  for (int o = 32; o > 0; o >>= 1) msum += __shfl_xor(msum, o);
  if (lane == 0) {
    redB[wave][0] = msum;
    #pragma unroll
    for (int c = 0; c < 64; c++) redA[wave][c] = qacc[c];
  }
  __syncthreads();
  if (tid < 64) {
    float qs = redA[0][tid] + redA[1][tid] + redA[2][tid] + redA[3][tid];
    float mt = redB[0][0] + redB[1][0] + redB[2][0] + redB[3][0];
    q_lds[tid] = qs / (mt + MEAN_EPS);
  }
  __syncthreads();
  if (tid < 64) {
    float acc = 0.f;
    for (int c = 0; c < 64; c++) acc = fmaf(q_lds[c], qw[c * 64 + tid], acc);
    qf_lds[tid] = acc * QSCALE;
  }
  __syncthreads();

  float qreg[64];
  #pragma unroll
  for (int j = 0; j < 64; j++) qreg[j] = qf_lds[j];
  float ev[4][8];
  float hm[8];
  #pragma unroll
  for (int h = 0; h < 8; h++) hm[h] = -1e30f;
  #pragma unroll
  for (int it = 0; it < 4; it++) {
    int s = tid + it * 256;
    union { uint4 u; _Float16 h[8]; } kb;
    kb.u = *reinterpret_cast<uint4*>(&sh.kv[s][0]);
    float kk[8];
    #pragma unroll
    for (int d = 0; d < 8; d++) kk[d] = (float)kb.h[d];
    float m = mask[(size_t)s * N_R + r];
    float bias = LARGE_F * (m - 1.f);
    #pragma unroll
    for (int h = 0; h < 8; h++) {
      float l = bias;
      #pragma unroll
      for (int d = 0; d < 8; d++) l = fmaf(qreg[h * 8 + d], kk[d], l);
      ev[it][h] = l;
      hm[h] = fmaxf(hm[h], l);
    }
  }
  #pragma unroll
  for (int h = 0; h < 8; h++) {
    #pragma unroll
    for (int o = 32; o > 0; o >>= 1) hm[h] = fmaxf(hm[h], __shfl_xor(hm[h], o));
  }
  if (lane == 0) {
    #pragma unroll
    for (int h = 0; h < 8; h++) redB[wave][h] = hm[h];
  }
  __syncthreads();
  #pragma unroll
  for (int h = 0; h < 8; h++)
    hm[h] = fmaxf(fmaxf(redB[0][h], redB[1][h]), fmaxf(redB[2][h], redB[3][h]));
  __syncthreads();

  float hs[8];
  #pragma unroll
  for (int h = 0; h < 8; h++) hs[h] = 0.f;
  #pragma unroll
  for (int it = 0; it < 4; it++) {
    #pragma unroll
    for (int h = 0; h < 8; h++) {
      float e = __expf(ev[it][h] - hm[h]);
      ev[it][h] = e;
      hs[h] += e;
    }
  }
  #pragma unroll
  for (int h = 0; h < 8; h++) {
    #pragma unroll
    for (int o = 32; o > 0; o >>= 1) hs[h] += __shfl_xor(hs[h], o);
  }
  if (lane == 0) {
    #pragma unroll
    for (int h = 0; h < 8; h++) redB[wave][h] = hs[h];
  }
  __syncthreads();

  float wacc[64];
  #pragma unroll
  for (int j = 0; j < 64; j++) wacc[j] = 0.f;
  #pragma unroll
  for (int it = 0; it < 4; it++) {
    int s = tid + it * 256;
    union { uint4 u; _Float16 h[8]; } vb;
    vb.u = *reinterpret_cast<uint4*>(&sh.kv[s][8]);
    float vv[8];
    #pragma unroll
    for (int d = 0; d < 8; d++) vv[d] = (float)vb.h[d];
    #pragma unroll
    for (int h = 0; h < 8; h++) {
      float w = ev[it][h];
      #pragma unroll
      for (int d = 0; d < 8; d++) wacc[h * 8 + d] = fmaf(w, vv[d], wacc[h * 8 + d]);
    }
  }
  #pragma unroll
  for (int j = 0; j < 64; j++) {
    #pragma unroll
    for (int o = 32; o > 0; o >>= 1) wacc[j] += __shfl_xor(wacc[j], o);
  }
  if (lane == 0) {
    #pragma unroll
    for (int j = 0; j < 64; j++) redA[wave][j] = wacc[j];
  }
  __syncthreads();
  if (tid < 64) {
    int h = tid >> 3;
    float hsv = redB[0][h] + redB[1][h] + redB[2][h] + redB[3][h];
    wavg_out[r * 64 + tid] =
        (redA[0][tid] + redA[1][tid] + redA[2][tid] + redA[3][tid]) / hsv;
  }
}

// ============ fallback proj (act-reading, known-good) ============
__device__ __forceinline__ void proj_tile(
    const float4 (&rv)[4], int t, int wv, int lane, int qr, int qc, int g, int c15,
    const float* __restrict__ lns, const float* __restrict__ lnb,
    const float* __restrict__ gb, const float* __restrict__ ob,
    const float* __restrict__ wavg, const uint4 (*wfrag)[64],
    char* my, float* __restrict__ out)
{
  const int r  = t >> 4;
  const int s0 = ((t & 15) << 6) + wv * 16;

  float sum = 0.f, ssq = 0.f;
  #pragma unroll
  for (int i = 0; i < 4; i++) {
    sum += rv[i].x + rv[i].y + rv[i].z + rv[i].w;
    ssq += rv[i].x * rv[i].x + rv[i].y * rv[i].y + rv[i].z * rv[i].z + rv[i].w * rv[i].w;
  }
  sum += __shfl_xor(sum, 1); ssq += __shfl_xor(ssq, 1);
  sum += __shfl_xor(sum, 2); ssq += __shfl_xor(ssq, 2);
  float mu  = sum * (1.f / 64.f);
  float rsd = rsqrtf(ssq * (1.f / 64.f) - mu * mu + LN_EPS);

  #pragma unroll
  for (int i = 0; i < 4; i++) {
    int c0 = 16 * i + 4 * qc;
    float4 s4 = *reinterpret_cast<const float4*>(lns + c0);
    float4 b4 = *reinterpret_cast<const float4*>(lnb + c0);
    float x0 = fmaf((rv[i].x - mu) * rsd, s4.x, b4.x);
    float x1 = fmaf((rv[i].y - mu) * rsd, s4.y, b4.y);
    float x2 = fmaf((rv[i].z - mu) * rsd, s4.z, b4.z);
    float x3 = fmaf((rv[i].w - mu) * rsd, s4.w, b4.w);
    uint2 p; p.x = pk2(x0, x1); p.y = pk2(x2, x3);
    int byt = ((2 * i + (qc >> 1)) << 8) + (qr << 4) + ((qc & 1) << 3);
    *reinterpret_cast<uint2*>(my + byt) = p;
  }
  asm volatile("" ::: "memory");
  bf16x8 xb0 = ld_frag(my + lane * 16);
  bf16x8 xb1 = ld_frag(my + 1024 + lane * 16);

  const f32x4 zero = {0.f, 0.f, 0.f, 0.f};
  f32x4 acc[4] = {zero, zero, zero, zero};
  #pragma unroll
  for (int mf = 0; mf < 4; mf++) {
    acc[mf] = __builtin_amdgcn_mfma_f32_16x16x32_bf16(ld_frag(&wfrag[     mf*2    ][lane]), xb0, acc[mf], 0, 0, 0);
    acc[mf] = __builtin_amdgcn_mfma_f32_16x16x32_bf16(ld_frag(&wfrag[ 8 + mf*2    ][lane]), xb0, acc[mf], 0, 0, 0);
    acc[mf] = __builtin_amdgcn_mfma_f32_16x16x32_bf16(ld_frag(&wfrag[     mf*2 + 1][lane]), xb1, acc[mf], 0, 0, 0);
    acc[mf] = __builtin_amdgcn_mfma_f32_16x16x32_bf16(ld_frag(&wfrag[ 8 + mf*2 + 1][lane]), xb1, acc[mf], 0, 0, 0);
  }

  asm volatile("" ::: "memory");
  #pragma unroll
  for (int mf = 0; mf < 4; mf++) {
    int jb = mf * 16 + 4 * g;
    float4 wv4 = *reinterpret_cast<const float4*>(wavg + r * 64 + jb);
    float4 gb4 = *reinterpret_cast<const float4*>(gb + jb);
    float c0 = wv4.x / (1.f + __expf(-(acc[mf][0] + gb4.x)));
    float c1 = wv4.y / (1.f + __expf(-(acc[mf][1] + gb4.y)));
    float c2 = wv4.z / (1.f + __expf(-(acc[mf][2] + gb4.z)));
    float c3 = wv4.w / (1.f + __expf(-(acc[mf][3] + gb4.w)));
    uint2 p; p.x = pk2(c0, c1); p.y = pk2(c2, c3);
    int byt = ((2 * mf + (g >> 1)) << 8) + (c15 << 4) + ((g & 1) << 3);
    *reinterpret_cast<uint2*>(my + byt) = p;
  }
  asm volatile("" ::: "memory");
  bf16x8 cb0 = ld_frag(my + lane * 16);
  bf16x8 cb1 = ld_frag(my + 1024 + lane * 16);

  f32x4 acc2[4] = {zero, zero, zero, zero};
  #pragma unroll
  for (int mf = 0; mf < 4; mf++) {
    acc2[mf] = __builtin_amdgcn_mfma_f32_16x16x32_bf16(ld_frag(&wfrag[16 + mf*2    ][lane]), cb0, acc2[mf], 0, 0, 0);
    acc2[mf] = __builtin_amdgcn_mfma_f32_16x16x32_bf16(ld_frag(&wfrag[24 + mf*2    ][lane]), cb0, acc2[mf], 0, 0, 0);
    acc2[mf] = __builtin_amdgcn_mfma_f32_16x16x32_bf16(ld_frag(&wfrag[16 + mf*2 + 1][lane]), cb1, acc2[mf], 0, 0, 0);
    acc2[mf] = __builtin_amdgcn_mfma_f32_16x16x32_bf16(ld_frag(&wfrag[24 + mf*2 + 1][lane]), cb1, acc2[mf], 0, 0, 0);
  }

  size_t obase = ((size_t)(s0 + c15) * N_R + r) * 64;
  #pragma unroll
  for (int mf = 0; mf < 4; mf++) {
    int o0 = mf * 16 + 4 * g;
    float4 e = *reinterpret_cast<const float4*>(ob + o0);
    float4 o4;
    o4.x = acc2[mf][0] + e.x;
    o4.y = acc2[mf][1] + e.y;
    o4.z = acc2[mf][2] + e.z;
    o4.w = acc2[mf][3] + e.w;
    *reinterpret_cast<float4*>(out + obase + o0) = o4;
  }
}

__global__ __launch_bounds__(256, 4) void proj_kernel(
    const float* __restrict__ act, const float* __restrict__ lns,
    const float* __restrict__ lnb, const float* __restrict__ gb,
    const float* __restrict__ ob,  const float* __restrict__ wavg,
    const uint4* __restrict__ wsf, float* __restrict__ out)
{
  __shared__ uint4 wfrag[32][64];
  __shared__ __align__(16) char wbuf[4][2048];

  const int tid  = threadIdx.x;
  const int lane = tid & 63;
  const int wv   = tid >> 6;
  const int b    = blockIdx.x;
  const int qr = lane >> 2, qc = lane & 3;
  const int g = lane >> 4, c15 = lane & 15;
  char* my = wbuf[wv];

  float4 rvA[4], rvB[4];
  {
    int t = b;
    const float4* ap = reinterpret_cast<const float4*>(
        act + ((size_t)((((t & 15) << 6) + wv * 16) + qr) * N_R + (t >> 4)) * 64);
    rvA[0] = ap[qc]; rvA[1] = ap[qc + 4]; rvA[2] = ap[qc + 8]; rvA[3] = ap[qc + 12];
  }
  {
    uint4* dst = &wfrag[0][0];
    #pragma unroll
    for (int i = 0; i < 8; i++) dst[tid + i * 256] = wsf[tid + i * 256];
  }
  __syncthreads();

  #pragma unroll 1
  for (int i = 0; i < 12; i += 2) {
    {
      int t = (i + 1) * 1024 + b;
      const float4* ap = reinterpret_cast<const float4*>(
          act + ((size_t)((((t & 15) << 6) + wv * 16) + qr) * N_R + (t >> 4)) * 64);
      rvB[0] = ap[qc]; rvB[1] = ap[qc + 4]; rvB[2] = ap[qc + 8]; rvB[3] = ap[qc + 12];
    }
    proj_tile(rvA, i * 1024 + b, wv, lane, qr, qc, g, c15, lns, lnb, gb, ob, wavg, wfrag, my, out);
    if (i + 2 < 12) {
      int t = (i + 2) * 1024 + b;
      const float4* ap = reinterpret_cast<const float4*>(
          act + ((size_t)((((t & 15) << 6) + wv * 16) + qr) * N_R + (t >> 4)) * 64);
      rvA[0] = ap[qc]; rvA[1] = ap[qc + 4]; rvA[2] = ap[qc + 8]; rvA[3] = ap[qc + 12];
    }
    proj_tile(rvB, (i + 1) * 1024 + b, wv, lane, qr, qc, g, c15, lns, lnb, gb, ob, wavg, wfrag, my, out);
  }
}

extern "C" void kernel_launch(void* const* d_in, const int* in_sizes, int n_in,
                              void* d_out, int out_size, void* d_ws, size_t ws_size,
                              hipStream_t stream)
{
  const float* act  = (const float*)d_in[0];
  const float* mask = (const float*)d_in[1];
  const float* lns  = (const float*)d_in[2];
  const float* lnb  = (const float*)d_in[3];
  const float* qw   = (const float*)d_in[4];
  const float* kw   = (const float*)d_in[5];
  const float* vw   = (const float*)d_in[6];
  const float* gw   = (const float*)d_in[7];
  const float* gb   = (const float*)d_in[8];
  const float* ow   = (const float*)d_in[9];
  const float* ob   = (const float*)d_in[10];

  char* ws = (char*)d_ws;
  float* wavg_ws = (float*)ws;                          // 196608
  uint4* wsf     = (uint4*)(ws + 196608);               // 32768
  const size_t OFF_KV  = 229376;                        // f16 [768][1024][16] = 25165824
  const size_t OFF_QP  = OFF_KV + 25165824;             // f32 [32][768][64]   = 6291456
  const size_t OFF_XNF = OFF_QP + 6291456;              // bf16 frags 49152 tiles * 2048 = 100663296
  const size_t NEED_MID = OFF_XNF;                      // 31686656
  const size_t NEED_BIG = OFF_XNF + 100663296;          // 132349952

  if (ws_size >= NEED_MID) {
    _Float16* kvws = (_Float16*)(ws + OFF_KV);
    float* qpart   = (float*)(ws + OFF_QP);
    uint4* xnf     = (uint4*)(ws + OFF_XNF);
    if (ws_size >= NEED_BIG) {
      lnkv2_kernel<true><<<1537, 256, 0, stream>>>(act, mask, lns, lnb, kw, vw, gw, ow,
                                                   kvws, qpart, xnf, wsf);
      softmax2_kernel<<<N_R, 256, 0, stream>>>(mask, qpart, qw, kvws, wavg_ws);
      proj2_kernel<<<1024, 256, 0, stream>>>(xnf, gb, ob, wavg_ws,
                                             (const uint4*)wsf, (float*)d_out);
    } else {
      lnkv2_kernel<false><<<1537, 256, 0, stream>>>(act, mask, lns, lnb, kw, vw, gw, ow,
                                                    kvws, qpart, xnf, wsf);
      softmax2_kernel<<<N_R, 256, 0, stream>>>(mask, qpart, qw, kvws, wavg_ws);
      proj_kernel<<<1024, 256, 0, stream>>>(act, lns, lnb, gb, ob,
                                            wavg_ws, (const uint4*)wsf, (float*)d_out);
    }
  } else {
    stats_kernel<<<N_R + 1, 256, 0, stream>>>(act, mask, lns, lnb, qw, kw, vw,
                                              gw, ow, wavg_ws, wsf);
    proj_kernel<<<1024, 256, 0, stream>>>(act, lns, lnb, gb, ob,
                                          wavg_ws, (const uint4*)wsf, (float*)d_out);
  }
}